// Round 1
// baseline (489.997 us; speedup 1.0000x reference)
//
#include <hip/hip_runtime.h>

#define BB 8
#define NN 256
#define FF 64

// ---------------------------------------------------------------------------
// P[r][f] = be[f] + sum_k x[r][k]*We[k][f]        (sender / i term, bias folded)
// Q[r][f] =         sum_k x[r][k]*We[64+k][f]     (receiver / j term)
// grid: B*N blocks, 64 threads
// ---------------------------------------------------------------------------
__global__ __launch_bounds__(64) void pq_kernel(
    const float* __restrict__ x, const float* __restrict__ We,
    const float* __restrict__ be, float* __restrict__ P, float* __restrict__ Q)
{
    const int r = blockIdx.x;
    const int f = threadIdx.x;
    __shared__ float xs[FF];
    xs[f] = x[r * FF + f];
    __syncthreads();
    float p = be[f];
    float q = 0.f;
#pragma unroll
    for (int k = 0; k < FF; ++k) {
        const float xv = xs[k];
        p = fmaf(xv, We[k * FF + f], p);
        q = fmaf(xv, We[(FF + k) * FF + f], q);
    }
    P[r * FF + f] = p;
    Q[r * FF + f] = q;
}

// ---------------------------------------------------------------------------
// Edge update, one block per (b,i) row. In-place capable (reads row fully
// into LDS chunks before epilogue writes).
//   MODE 0: write e_out, write agg[b,i,f] = (sum_j e_new)/deg
//   MODE 1: write e_out only
//   MODE 2: no e_out; atomicAdd v[b][f] += sum_j e_new
// 256 threads: thread (tf,tj) computes 8f x 8j register tile.
// ---------------------------------------------------------------------------
template <int MODE>
__global__ __launch_bounds__(256) void edge_kernel(
    const float* __restrict__ e_in, const float* __restrict__ Wc,
    const float* __restrict__ P, const float* __restrict__ Q,
    const int* __restrict__ A, float* __restrict__ e_out,
    float* __restrict__ red_out)
{
    __shared__ float Wl[FF * FF];     // 16 KB  W[k][f]
    __shared__ float el[16 * NN];     // 16 KB  e_t[k][j], k-chunk of 16
    __shared__ float Pl[FF];
    __shared__ float Al[NN];
    __shared__ float red[FF];
    __shared__ float degsh;

    const int tid = threadIdx.x;
    const int bi  = blockIdx.x;     // b*N + i
    const int b   = bi >> 8;

    // ---- stage W / A-row / P-row ----
    {
        const float4* Ws = (const float4*)Wc;
        float4*       Wd = (float4*)Wl;
#pragma unroll
        for (int m = 0; m < 4; ++m) Wd[tid + m * 256] = Ws[tid + m * 256];
    }
    Al[tid] = (float)A[bi * NN + tid];
    if (tid < FF) {
        Pl[tid] = P[bi * FF + tid];
        if (MODE != 1) red[tid] = 0.f;
    }
    __syncthreads();

    if (MODE == 0) {
        if (tid < 64) {
            float s = Al[tid] + Al[tid + 64] + Al[tid + 128] + Al[tid + 192];
#pragma unroll
            for (int off = 32; off > 0; off >>= 1) s += __shfl_down(s, off, 64);
            if (tid == 0) degsh = fmaxf(s, 1.0f);
        }
    }

    const int tj = tid & 31;
    const int tf = tid >> 5;
    const int j0 = tj * 8;
    const int f0 = tf * 8;

    float acc[8][8];
#pragma unroll
    for (int a = 0; a < 8; ++a)
#pragma unroll
        for (int c = 0; c < 8; ++c) acc[a][c] = 0.f;

    const float* erow = e_in + (size_t)bi * NN * FF;

    for (int kc = 0; kc < 4; ++kc) {
        __syncthreads();  // previous chunk's reads complete
        const float4* src = (const float4*)(erow + tid * FF + kc * 16);
#pragma unroll
        for (int m = 0; m < 4; ++m) {
            const float4 v = src[m];
            el[(m * 4 + 0) * NN + tid] = v.x;
            el[(m * 4 + 1) * NN + tid] = v.y;
            el[(m * 4 + 2) * NN + tid] = v.z;
            el[(m * 4 + 3) * NN + tid] = v.w;
        }
        __syncthreads();
#pragma unroll
        for (int kk = 0; kk < 16; ++kk) {
            const int k = kc * 16 + kk;
            const float4 w0 = *(const float4*)&Wl[k * FF + f0];
            const float4 w1 = *(const float4*)&Wl[k * FF + f0 + 4];
            const float4 e0 = *(const float4*)&el[kk * NN + j0];
            const float4 e1 = *(const float4*)&el[kk * NN + j0 + 4];
            const float ev[8] = {e0.x, e0.y, e0.z, e0.w, e1.x, e1.y, e1.z, e1.w};
            const float wv[8] = {w0.x, w0.y, w0.z, w0.w, w1.x, w1.y, w1.z, w1.w};
#pragma unroll
            for (int jj = 0; jj < 8; ++jj)
#pragma unroll
                for (int ff = 0; ff < 8; ++ff)
                    acc[jj][ff] = fmaf(ev[jj], wv[ff], acc[jj][ff]);
        }
    }

    // ---- epilogue ----
    float psum[8];
#pragma unroll
    for (int ff = 0; ff < 8; ++ff) psum[ff] = 0.f;

    const float* Qb   = Q + (size_t)b * NN * FF;
    float*       orow = (MODE == 2) ? nullptr : (e_out + (size_t)bi * NN * FF);

#pragma unroll
    for (int jj = 0; jj < 8; ++jj) {
        const int   j = j0 + jj;
        const float a = Al[j];
        const float4 q0 = *(const float4*)(Qb + j * FF + f0);
        const float4 q1 = *(const float4*)(Qb + j * FF + f0 + 4);
        const float qv[8] = {q0.x, q0.y, q0.z, q0.w, q1.x, q1.y, q1.z, q1.w};
        float r[8];
#pragma unroll
        for (int ff = 0; ff < 8; ++ff) {
            const float t = acc[jj][ff] + Pl[f0 + ff] + qv[ff];
            r[ff] = fmaxf(t, 0.f) * a;
            psum[ff] += r[ff];
        }
        if (MODE != 2) {
            *(float4*)(orow + j * FF + f0)     = make_float4(r[0], r[1], r[2], r[3]);
            *(float4*)(orow + j * FF + f0 + 4) = make_float4(r[4], r[5], r[6], r[7]);
        }
    }

    if (MODE != 1) {
#pragma unroll
        for (int ff = 0; ff < 8; ++ff) atomicAdd(&red[f0 + ff], psum[ff]);
        __syncthreads();
        if (MODE == 0) {
            if (tid < FF) red_out[bi * FF + tid] = red[tid] / degsh;
        } else {
            if (tid < FF) atomicAdd(&red_out[b * FF + tid], red[tid]);
        }
    }
}

// ---------------------------------------------------------------------------
// x1[r][f] = relu(bn[f] + sum_k x[r][k]*Wn[k][f] + agg[r][k]*Wn[64+k][f])
// ---------------------------------------------------------------------------
__global__ __launch_bounds__(64) void node_kernel(
    const float* __restrict__ x, const float* __restrict__ agg,
    const float* __restrict__ Wn, const float* __restrict__ bn,
    float* __restrict__ x1)
{
    const int r = blockIdx.x;
    const int f = threadIdx.x;
    __shared__ float s[2 * FF];
    s[f]      = x[r * FF + f];
    s[FF + f] = agg[r * FF + f];
    __syncthreads();
    float acc = bn[f];
#pragma unroll
    for (int k = 0; k < 2 * FF; ++k) acc = fmaf(s[k], Wn[k * FF + f], acc);
    x1[r * FF + f] = fmaxf(acc, 0.f);
}

// ---------------------------------------------------------------------------
// MLP head: v(sum) -> /65536 -> relu(@W1+b1) -> relu(@W2+b2) -> @W3+b3
// single block, 64 threads (one wave)
// ---------------------------------------------------------------------------
__global__ __launch_bounds__(64) void head_kernel(
    const float* __restrict__ vsum, const float* __restrict__ W1,
    const float* __restrict__ b1, const float* __restrict__ W2,
    const float* __restrict__ b2, const float* __restrict__ W3,
    const float* __restrict__ b3, float* __restrict__ out)
{
    const int f = threadIdx.x;
    __shared__ float hv[BB][FF];
    __shared__ float h1[BB][FF];
#pragma unroll
    for (int b = 0; b < BB; ++b) hv[b][f] = vsum[b * FF + f] * (1.0f / 65536.0f);
    __syncthreads();
#pragma unroll
    for (int b = 0; b < BB; ++b) {
        float acc = b1[f];
#pragma unroll
        for (int k = 0; k < FF; ++k) acc = fmaf(hv[b][k], W1[k * FF + f], acc);
        h1[b][f] = fmaxf(acc, 0.f);
    }
    __syncthreads();
#pragma unroll
    for (int b = 0; b < BB; ++b) {
        float acc = b2[f];
#pragma unroll
        for (int k = 0; k < FF; ++k) acc = fmaf(h1[b][k], W2[k * FF + f], acc);
        hv[b][f] = fmaxf(acc, 0.f);  // reuse as h2
    }
    __syncthreads();
#pragma unroll
    for (int b = 0; b < BB; ++b) {
        float p = hv[b][f] * W3[f];
#pragma unroll
        for (int off = 32; off > 0; off >>= 1) p += __shfl_down(p, off, 64);
        if (f == 0) out[b] = p + b3[0];
    }
}

// ---------------------------------------------------------------------------
extern "C" void kernel_launch(void* const* d_in, const int* in_sizes, int n_in,
                              void* d_out, int out_size, void* d_ws, size_t ws_size,
                              hipStream_t stream)
{
    const int*   A      = (const int*)d_in[0];
    const float* x      = (const float*)d_in[1];
    float*       e_attr = (float*)d_in[2];   // updated in place (restored by harness)

    const float* We[3] = {(const float*)d_in[3], (const float*)d_in[7],  (const float*)d_in[11]};
    const float* be[3] = {(const float*)d_in[4], (const float*)d_in[8],  (const float*)d_in[12]};
    const float* Wn[3] = {(const float*)d_in[5], (const float*)d_in[9],  (const float*)d_in[13]};
    const float* bn[3] = {(const float*)d_in[6], (const float*)d_in[10], (const float*)d_in[14]};
    const float* W1 = (const float*)d_in[15];
    const float* b1 = (const float*)d_in[16];
    const float* W2 = (const float*)d_in[17];
    const float* b2 = (const float*)d_in[18];
    const float* W3 = (const float*)d_in[19];
    const float* b3 = (const float*)d_in[20];
    float* out = (float*)d_out;

    // small workspace layout (floats)
    float* P   = (float*)d_ws;                  // 2048*64
    float* Qb  = P   + BB * NN * FF;            // 2048*64
    float* agg = Qb  + BB * NN * FF;            // 2048*64
    float* x1  = agg + BB * NN * FF;            // 2048*64
    float* v   = x1  + BB * NN * FF;            // 8*64
    (void)in_sizes; (void)n_in; (void)out_size; (void)ws_size;

    hipMemsetAsync(v, 0, BB * FF * sizeof(float), stream);

    const int RB = BB * NN;  // 2048 rows

    // layer 0: nodes + edges (in place on e_attr)
    pq_kernel<<<RB, 64, 0, stream>>>(x, We[0], be[0], P, Qb);
    edge_kernel<0><<<RB, 256, 0, stream>>>(e_attr, We[0] + 2 * FF * FF, P, Qb, A,
                                           e_attr, agg);
    node_kernel<<<RB, 64, 0, stream>>>(x, agg, Wn[0], bn[0], x1);

    // layer 1: edges only (node output discarded)
    pq_kernel<<<RB, 64, 0, stream>>>(x1, We[1], be[1], P, Qb);
    edge_kernel<1><<<RB, 256, 0, stream>>>(e_attr, We[1] + 2 * FF * FF, P, Qb, A,
                                           e_attr, nullptr);

    // layer 2: edges reduced straight to v (never materialized)
    pq_kernel<<<RB, 64, 0, stream>>>(x1, We[2], be[2], P, Qb);
    edge_kernel<2><<<RB, 256, 0, stream>>>(e_attr, We[2] + 2 * FF * FF, P, Qb, A,
                                           nullptr, v);

    // head
    head_kernel<<<1, 64, 0, stream>>>(v, W1, b1, W2, b2, W3, b3, out);
}